// Round 1
// baseline (143.576 us; speedup 1.0000x reference)
//
#include <hip/hip_runtime.h>

// Problem: B=4, Sx=Sy=512, H=128, D=2H=256, all fp32.
// s1 = x @ Wc1^T  (B*Sx, 128); s2 = y @ Wc2^T (B*Sy, 128)
// score[b,t,s] = sum_h vc[h]*tanh(s1[b,s,h]+s2[b,t,h])
// P = softmax_s(score); out[b,t,:] = P[b,t,:] @ x[b]
//
// tanh(z) = 1 - 2/(exp2(2*log2e*z)+1). Pre-scale s1,s2 by 2*log2e in kernel A.
// sum_h vc[h] is constant across s -> cancels in softmax, dropped.

#define NB 4
#define SEQ 512
#define HDIM 128
#define DDIM 256

static constexpr float TWO_LOG2E = 2.8853900817779268f; // 2*log2(e)
static constexpr float LOG2E     = 1.4426950408889634f;

// ---------------- Kernel A: projections -----------------------------------
// 4096 virtual rows (2048 from x, 2048 from y). 16 rows per block, 256 blocks.
// Tile: 16 rows x 128 h, K=256 in chunks of 64. As[k][r] stride 17, Bs[k][h]
// stride 132 (16B-aligned float4 reads along h).
__global__ __launch_bounds__(256) void proj_kernel(
    const float* __restrict__ x, const float* __restrict__ y,
    const float* __restrict__ W1, const float* __restrict__ W2,
    float* __restrict__ s1p, float* __restrict__ s2p)
{
    __shared__ float As[64 * 17];
    __shared__ float Bs[64 * 132];
    const int tid = threadIdx.x;
    const int blk = blockIdx.x;      // 0..255

    const float* in;  const float* W;  float* outp;  int rbase;
    if (blk < 128) { in = x; W = W1; outp = s1p; rbase = blk * 16; }
    else           { in = y; W = W2; outp = s2p; rbase = (blk - 128) * 16; }

    const int ty = tid >> 5;   // 0..7 -> rows 2ty, 2ty+1
    const int tx = tid & 31;   // h = 4*tx .. 4*tx+3

    float acc[2][4] = {{0.f,0.f,0.f,0.f},{0.f,0.f,0.f,0.f}};

    for (int kc = 0; kc < 256; kc += 64) {
        __syncthreads();
        // stage A tile: 16 rows x 64 k = 1024 floats (1 float4/thread)
        {
            const int r = tid >> 4, kq = tid & 15;
            const float4 v = *(const float4*)&in[(rbase + r) * 256 + kc + kq * 4];
            As[(4*kq + 0) * 17 + r] = v.x;
            As[(4*kq + 1) * 17 + r] = v.y;
            As[(4*kq + 2) * 17 + r] = v.z;
            As[(4*kq + 3) * 17 + r] = v.w;
        }
        // stage B tile: 128 h x 64 k = 8192 floats (8 float4/thread)
        #pragma unroll
        for (int j = 0; j < 8; ++j) {
            const int i = tid + j * 256;
            const int h = i >> 4, kq = i & 15;
            const float4 v = *(const float4*)&W[h * 256 + kc + kq * 4];
            Bs[(4*kq + 0) * 132 + h] = v.x;
            Bs[(4*kq + 1) * 132 + h] = v.y;
            Bs[(4*kq + 2) * 132 + h] = v.z;
            Bs[(4*kq + 3) * 132 + h] = v.w;
        }
        __syncthreads();
        #pragma unroll 16
        for (int k = 0; k < 64; ++k) {
            const float a0 = As[k * 17 + 2*ty];
            const float a1 = As[k * 17 + 2*ty + 1];
            const float4 bv = *(const float4*)&Bs[k * 132 + 4*tx];
            acc[0][0] = fmaf(a0, bv.x, acc[0][0]);
            acc[0][1] = fmaf(a0, bv.y, acc[0][1]);
            acc[0][2] = fmaf(a0, bv.z, acc[0][2]);
            acc[0][3] = fmaf(a0, bv.w, acc[0][3]);
            acc[1][0] = fmaf(a1, bv.x, acc[1][0]);
            acc[1][1] = fmaf(a1, bv.y, acc[1][1]);
            acc[1][2] = fmaf(a1, bv.z, acc[1][2]);
            acc[1][3] = fmaf(a1, bv.w, acc[1][3]);
        }
    }
    #pragma unroll
    for (int rr = 0; rr < 2; ++rr) {
        const int row = rbase + 2*ty + rr;
        float4 o;
        o.x = acc[rr][0] * TWO_LOG2E;
        o.y = acc[rr][1] * TWO_LOG2E;
        o.z = acc[rr][2] * TWO_LOG2E;
        o.w = acc[rr][3] * TWO_LOG2E;
        *(float4*)&outp[row * HDIM + 4*tx] = o;
    }
}

// ---------------- Kernel B: scores + softmax ------------------------------
// Block = (b, 4 consecutive t rows). 512 blocks x 256 threads (4 waves).
// Wave w owns t = t0+w; lane = s within a 64-s chunk. s1 chunk staged
// transposed [h][s] stride 65 (bank = (h+s)%32 -> 2-way alias = free).
__global__ __launch_bounds__(256) void score_kernel(
    const float* __restrict__ s1p, const float* __restrict__ s2p,
    const float* __restrict__ vc, float* __restrict__ P)
{
    __shared__ float sS1[128 * 65];
    __shared__ float sS2[4 * 128];
    __shared__ float sVc2[128];
    __shared__ float sP[4 * 512];

    const int tid = threadIdx.x;
    const int b  = blockIdx.x >> 7;
    const int t0 = (blockIdx.x & 127) * 4;

    // preload the 4 s2' rows + vc2 = -2*vc
    #pragma unroll
    for (int i = tid; i < 512; i += 256)
        sS2[i] = s2p[(b * SEQ + t0 + (i >> 7)) * HDIM + (i & 127)];
    if (tid < 128) sVc2[tid] = -2.0f * vc[tid];

    const int t = tid >> 6, lane = tid & 63;
    const float* s2t = &sS2[t * 128];

    for (int c = 0; c < 8; ++c) {
        const int s0 = c * 64;
        __syncthreads();
        // stage s1'[b, s0..s0+63, :] transposed into sS1[h][s]
        #pragma unroll
        for (int j = 0; j < 8; ++j) {
            const int i = tid + j * 256;
            const int sl = i >> 5, hq = i & 31;
            const float4 v = *(const float4*)&s1p[(b * SEQ + s0 + sl) * HDIM + hq * 4];
            sS1[(4*hq + 0) * 65 + sl] = v.x;
            sS1[(4*hq + 1) * 65 + sl] = v.y;
            sS1[(4*hq + 2) * 65 + sl] = v.z;
            sS1[(4*hq + 3) * 65 + sl] = v.w;
        }
        __syncthreads();
        float acc = 0.f;
        #pragma unroll 8
        for (int h = 0; h < 128; ++h) {
            const float u = sS1[h * 65 + lane] + s2t[h];
            const float e = __builtin_amdgcn_exp2f(u);
            const float r = __builtin_amdgcn_rcpf(e + 1.0f);
            acc = fmaf(sVc2[h], r, acc);
        }
        sP[t * 512 + s0 + lane] = acc;
    }

    // per-wave softmax over this wave's own 512 scores (no cross-wave dep)
    float v[8];
    float m = -1e30f;
    #pragma unroll
    for (int j = 0; j < 8; ++j) {
        v[j] = sP[t * 512 + lane + j * 64];
        m = fmaxf(m, v[j]);
    }
    #pragma unroll
    for (int off = 32; off > 0; off >>= 1) m = fmaxf(m, __shfl_xor(m, off));
    float sum = 0.f;
    #pragma unroll
    for (int j = 0; j < 8; ++j) {
        v[j] = __builtin_amdgcn_exp2f((v[j] - m) * LOG2E);
        sum += v[j];
    }
    #pragma unroll
    for (int off = 32; off > 0; off >>= 1) sum += __shfl_xor(sum, off);
    const float inv = __builtin_amdgcn_rcpf(sum);
    float* Prow = &P[(b * SEQ + t0 + t) * SEQ];
    #pragma unroll
    for (int j = 0; j < 8; ++j) Prow[lane + j * 64] = v[j] * inv;
}

// ---------------- Kernel C: out = P @ x -----------------------------------
// Block = (b, 8 t rows). 256 blocks x 256 threads. x staged 64 s at a time
// (64 KiB LDS), each wave handles 2 t rows, lane covers a float4 of d.
__global__ __launch_bounds__(256) void out_kernel(
    const float* __restrict__ P, const float* __restrict__ x,
    float* __restrict__ out)
{
    __shared__ float Xs[64 * 256];
    const int tid = threadIdx.x;
    const int b  = blockIdx.x >> 6;
    const int t0 = (blockIdx.x & 63) * 8;
    const int tg = tid >> 6;          // wave id 0..3
    const int d4 = (tid & 63) * 4;
    const int ta = t0 + tg * 2, tb = ta + 1;
    const float* Pa = &P[(b * SEQ + ta) * SEQ];
    const float* Pb = &P[(b * SEQ + tb) * SEQ];

    float4 acc0 = {0.f,0.f,0.f,0.f}, acc1 = {0.f,0.f,0.f,0.f};

    for (int c = 0; c < 8; ++c) {
        const int s0 = c * 64;
        __syncthreads();
        #pragma unroll
        for (int j = 0; j < 16; ++j) {
            const int i = tid + j * 256;
            const int s = i >> 6, dq = i & 63;
            *(float4*)&Xs[s * 256 + dq * 4] =
                *(const float4*)&x[(b * SEQ + s0 + s) * DDIM + dq * 4];
        }
        __syncthreads();
        #pragma unroll 8
        for (int s = 0; s < 64; ++s) {
            const float p0 = Pa[s0 + s];
            const float p1 = Pb[s0 + s];
            const float4 xv = *(const float4*)&Xs[s * 256 + d4];
            acc0.x = fmaf(p0, xv.x, acc0.x);
            acc0.y = fmaf(p0, xv.y, acc0.y);
            acc0.z = fmaf(p0, xv.z, acc0.z);
            acc0.w = fmaf(p0, xv.w, acc0.w);
            acc1.x = fmaf(p1, xv.x, acc1.x);
            acc1.y = fmaf(p1, xv.y, acc1.y);
            acc1.z = fmaf(p1, xv.z, acc1.z);
            acc1.w = fmaf(p1, xv.w, acc1.w);
        }
    }
    *(float4*)&out[(b * SEQ + ta) * DDIM + d4] = acc0;
    *(float4*)&out[(b * SEQ + tb) * DDIM + d4] = acc1;
}

extern "C" void kernel_launch(void* const* d_in, const int* in_sizes, int n_in,
                              void* d_out, int out_size, void* d_ws, size_t ws_size,
                              hipStream_t stream) {
    const float* x   = (const float*)d_in[0];   // (4,512,256)
    const float* y   = (const float*)d_in[1];   // (4,512,256)
    const float* W1  = (const float*)d_in[2];   // (128,256)
    const float* W2  = (const float*)d_in[3];   // (128,256)
    const float* vc  = (const float*)d_in[4];   // (1,128)
    float* outp = (float*)d_out;                // (4,512,256)

    float* ws  = (float*)d_ws;
    float* s1p = ws;                            // 4*512*128
    float* s2p = ws + NB * SEQ * HDIM;          // 4*512*128
    float* P   = ws + 2 * NB * SEQ * HDIM;      // 4*512*512

    hipLaunchKernelGGL(proj_kernel,  dim3(256), dim3(256), 0, stream,
                       x, y, W1, W2, s1p, s2p);
    hipLaunchKernelGGL(score_kernel, dim3(512), dim3(256), 0, stream,
                       s1p, s2p, vc, P);
    hipLaunchKernelGGL(out_kernel,   dim3(256), dim3(256), 0, stream,
                       P, x, outp);
}

// Round 2
// 134.997 us; speedup vs baseline: 1.0635x; 1.0635x over previous
//
#include <hip/hip_runtime.h>

// B=4, Sx=Sy=512, H=128, D=2H=256, fp32.
// s1 = x@Wc1^T, s2 = y@Wc2^T
// score[b,t,s] = sum_h vc[h]*tanh(s1[b,s,h]+s2[b,t,h]);  P = softmax_s(score)
// out[b,t,:] = P[b,t,:] @ x[b]
//
// tanh(u) = 1 - 2/(e^{2u}+1);  e^{2(s1+s2)} = e1*e2 with e1=exp2(2log2e*s1),
// e2=exp2(2log2e*s2) precomputed in proj epilogue. Sum_h vc[h] is softmax-
// invariant -> dropped. Pairs of h share one rcp:
//   a/f1 + b/f2 = (a*f2 + b*f1) / (f1*f2).

#define NB 4
#define SEQ 512
#define HDIM 128
#define DDIM 256

static constexpr float TWO_LOG2E = 2.8853900817779268f; // 2*log2(e)
static constexpr float LOG2E     = 1.4426950408889634f;

// ---------------- Kernel A: projections + exp2 epilogue --------------------
__global__ __launch_bounds__(256) void proj_kernel(
    const float* __restrict__ x, const float* __restrict__ y,
    const float* __restrict__ W1, const float* __restrict__ W2,
    float* __restrict__ e1out, float* __restrict__ e2out)
{
    __shared__ float As[64 * 17];
    __shared__ float Bs[64 * 132];
    const int tid = threadIdx.x;
    const int blk = blockIdx.x;      // 0..255

    const float* in;  const float* W;  float* outp;  int rbase;
    if (blk < 128) { in = x; W = W1; outp = e1out; rbase = blk * 16; }
    else           { in = y; W = W2; outp = e2out; rbase = (blk - 128) * 16; }

    const int ty = tid >> 5;   // 0..7 -> rows 2ty, 2ty+1
    const int tx = tid & 31;   // h = 4*tx .. 4*tx+3

    float acc[2][4] = {{0.f,0.f,0.f,0.f},{0.f,0.f,0.f,0.f}};

    for (int kc = 0; kc < 256; kc += 64) {
        __syncthreads();
        {
            const int r = tid >> 4, kq = tid & 15;
            const float4 v = *(const float4*)&in[(rbase + r) * 256 + kc + kq * 4];
            As[(4*kq + 0) * 17 + r] = v.x;
            As[(4*kq + 1) * 17 + r] = v.y;
            As[(4*kq + 2) * 17 + r] = v.z;
            As[(4*kq + 3) * 17 + r] = v.w;
        }
        #pragma unroll
        for (int j = 0; j < 8; ++j) {
            const int i = tid + j * 256;
            const int h = i >> 4, kq = i & 15;
            const float4 v = *(const float4*)&W[h * 256 + kc + kq * 4];
            Bs[(4*kq + 0) * 132 + h] = v.x;
            Bs[(4*kq + 1) * 132 + h] = v.y;
            Bs[(4*kq + 2) * 132 + h] = v.z;
            Bs[(4*kq + 3) * 132 + h] = v.w;
        }
        __syncthreads();
        #pragma unroll 16
        for (int k = 0; k < 64; ++k) {
            const float a0 = As[k * 17 + 2*ty];
            const float a1 = As[k * 17 + 2*ty + 1];
            const float4 bv = *(const float4*)&Bs[k * 132 + 4*tx];
            acc[0][0] = fmaf(a0, bv.x, acc[0][0]);
            acc[0][1] = fmaf(a0, bv.y, acc[0][1]);
            acc[0][2] = fmaf(a0, bv.z, acc[0][2]);
            acc[0][3] = fmaf(a0, bv.w, acc[0][3]);
            acc[1][0] = fmaf(a1, bv.x, acc[1][0]);
            acc[1][1] = fmaf(a1, bv.y, acc[1][1]);
            acc[1][2] = fmaf(a1, bv.z, acc[1][2]);
            acc[1][3] = fmaf(a1, bv.w, acc[1][3]);
        }
    }
    #pragma unroll
    for (int rr = 0; rr < 2; ++rr) {
        const int row = rbase + 2*ty + rr;
        float4 o;
        o.x = __builtin_amdgcn_exp2f(acc[rr][0] * TWO_LOG2E);
        o.y = __builtin_amdgcn_exp2f(acc[rr][1] * TWO_LOG2E);
        o.z = __builtin_amdgcn_exp2f(acc[rr][2] * TWO_LOG2E);
        o.w = __builtin_amdgcn_exp2f(acc[rr][3] * TWO_LOG2E);
        *(float4*)&outp[row * HDIM + 4*tx] = o;
    }
}

// ---------------- Kernel B: fused scores + softmax + P@x -------------------
// Block = (b, 4 t rows), 512 threads = 8 waves. Grid = 512 blocks (2/CU,
// 16 waves/CU). Wave w: t = w&3, h-half = w>>2. e1 staged transposed as
// float2 h-pairs [hp][s] stride 65 (b64 reads conflict-free). Partial scores
// combined in LDS; waves 0-3 do softmax; x staged through the same LDS
// region (aliased) for the P@x phase. P never touches global memory.
__global__ __launch_bounds__(512, 4) void attn_kernel(
    const float* __restrict__ e1g, const float* __restrict__ e2g,
    const float* __restrict__ vc,  const float* __restrict__ x,
    float* __restrict__ out)
{
    __shared__ float2 sE1p[64 * 65];      // 33280 B; aliased as Xs[32*256] floats
    __shared__ float  sE2[4 * 128];       // e2 rows for the 4 t
    __shared__ float  sVc2[128];          // -2*vc
    __shared__ float  sPart[2 * 4 * 512]; // 16 KB; aliased as sPn[512*4] after

    const int tid  = threadIdx.x;
    const int b    = blockIdx.x >> 7;
    const int t0   = (blockIdx.x & 127) * 4;
    const int w    = tid >> 6;     // 0..7
    const int lane = tid & 63;
    const int t    = w & 3;
    const int hh   = w >> 2;       // h-half

    // preload e2 rows + vc2 (visible after first loop barrier)
    sE2[tid & 511] = e2g[(b * SEQ + t0 + (tid >> 7)) * HDIM + (tid & 127)];
    if (tid < 128) sVc2[tid] = -2.0f * vc[tid];

    const float2* e2tp  = (const float2*)&sE2[t * 128];
    const float2* vc2p  = (const float2*)sVc2;

    // ---- score phase ----
    for (int c = 0; c < 8; ++c) {
        const int s0 = c * 64;
        __syncthreads();
        #pragma unroll
        for (int j = 0; j < 4; ++j) {
            const int i  = tid + j * 512;
            const int sl = i >> 5, hq = i & 31;
            const float4 v = *(const float4*)&e1g[(b * SEQ + s0 + sl) * HDIM + hq * 4];
            sE1p[(2*hq + 0) * 65 + sl] = make_float2(v.x, v.y);
            sE1p[(2*hq + 1) * 65 + sl] = make_float2(v.z, v.w);
        }
        __syncthreads();
        float acc = 0.f;
        #pragma unroll 8
        for (int hp = 0; hp < 32; ++hp) {
            const int gp = hh * 32 + hp;
            const float2 e1 = sE1p[gp * 65 + lane];
            const float2 e2 = e2tp[gp];
            const float2 a  = vc2p[gp];
            const float f1 = fmaf(e1.x, e2.x, 1.0f);
            const float f2 = fmaf(e1.y, e2.y, 1.0f);
            const float n  = fmaf(a.x, f2, a.y * f1);
            acc = fmaf(n, __builtin_amdgcn_rcpf(f1 * f2), acc);
        }
        sPart[hh * 2048 + t * 512 + s0 + lane] = acc;
    }
    __syncthreads();   // all partials visible

    // ---- softmax (waves 0-3, t = w) ----
    float v[8];
    float inv = 0.f;
    if (w < 4) {
        float m = -1e30f;
        #pragma unroll
        for (int j = 0; j < 8; ++j) {
            const int s = lane + j * 64;
            v[j] = sPart[t * 512 + s] + sPart[2048 + t * 512 + s];
            m = fmaxf(m, v[j]);
        }
        #pragma unroll
        for (int off = 32; off; off >>= 1) m = fmaxf(m, __shfl_xor(m, off));
        float sum = 0.f;
        #pragma unroll
        for (int j = 0; j < 8; ++j) {
            v[j] = __builtin_amdgcn_exp2f((v[j] - m) * LOG2E);
            sum += v[j];
        }
        #pragma unroll
        for (int off = 32; off; off >>= 1) sum += __shfl_xor(sum, off);
        inv = __builtin_amdgcn_rcpf(sum);
    }
    __syncthreads();   // sPart reads done before overwrite
    float* sPn = sPart;            // [s][4] normalized probs
    if (w < 4) {
        #pragma unroll
        for (int j = 0; j < 8; ++j)
            sPn[(lane + j * 64) * 4 + t] = v[j] * inv;
    }

    // ---- P@x phase: wave w -> d-quarter (w&3), t-pair (w>>2) ----
    float* Xs = (float*)sE1p;      // [32 s][256 d]
    const int dq = w & 3;
    const int tp = w >> 2;
    const int d  = dq * 64 + lane;
    float acc0 = 0.f, acc1 = 0.f;

    for (int cc = 0; cc < 16; ++cc) {
        __syncthreads();           // sPn visible (cc==0); Xs reuse safe
        #pragma unroll
        for (int j = 0; j < 4; ++j) {
            const int i  = tid + j * 512;
            const int sl = i >> 6, dqq = i & 63;
            *(float4*)&Xs[sl * 256 + dqq * 4] =
                *(const float4*)&x[(b * SEQ + cc * 32 + sl) * DDIM + dqq * 4];
        }
        __syncthreads();
        #pragma unroll 8
        for (int si = 0; si < 32; ++si) {
            const float  xv = Xs[si * 256 + d];
            const float2 p  = *(const float2*)&sPn[(cc * 32 + si) * 4 + 2 * tp];
            acc0 = fmaf(p.x, xv, acc0);
            acc1 = fmaf(p.y, xv, acc1);
        }
    }
    out[(b * SEQ + t0 + 2 * tp + 0) * DDIM + d] = acc0;
    out[(b * SEQ + t0 + 2 * tp + 1) * DDIM + d] = acc1;
}

extern "C" void kernel_launch(void* const* d_in, const int* in_sizes, int n_in,
                              void* d_out, int out_size, void* d_ws, size_t ws_size,
                              hipStream_t stream) {
    const float* x   = (const float*)d_in[0];   // (4,512,256)
    const float* y   = (const float*)d_in[1];   // (4,512,256)
    const float* W1  = (const float*)d_in[2];   // (128,256)
    const float* W2  = (const float*)d_in[3];   // (128,256)
    const float* vc  = (const float*)d_in[4];   // (1,128)
    float* outp = (float*)d_out;                // (4,512,256)

    float* ws  = (float*)d_ws;
    float* e1  = ws;                            // 4*512*128
    float* e2  = ws + NB * SEQ * HDIM;          // 4*512*128

    hipLaunchKernelGGL(proj_kernel, dim3(256), dim3(256), 0, stream,
                       x, y, W1, W2, e1, e2);
    hipLaunchKernelGGL(attn_kernel, dim3(512), dim3(512), 0, stream,
                       e1, e2, vc, x, outp);
}